// Round 8
// baseline (216.951 us; speedup 1.0000x reference)
//
#include <hip/hip_runtime.h>
#include <math.h>

#define D 128
#define GRAPHS 64

typedef __attribute__((ext_vector_type(8))) short bf16x8;
typedef __attribute__((ext_vector_type(4))) float f32x4;

union U4H8 { uint4 u; bf16x8 h; };

__device__ __forceinline__ unsigned short f2bf(float f) {   // RNE
  union { float f; unsigned u; } v; v.f = f;
  unsigned r = v.u + 0x7fffu + ((v.u >> 16) & 1u);
  return (unsigned short)(r >> 16);
}
__device__ __forceinline__ unsigned asu(float f) {
  union { float f; unsigned u; } v; v.f = f; return v.u;
}
__device__ __forceinline__ float asf(unsigned u) {
  union { unsigned u; float f; } v; v.u = u; return v.f;
}

// ---------------------------------------------------------------------------
// Gram partials: grid = GRAPHS*KS x 256 thr (4 waves). Block (g,sl): fp32
// register X_sl^T X_sl over chunk=L/KS rows; 64-row K-chunks. Staging layout:
// slice (ks*8+t) of 64 chunks; chunk (qs,lnw) at position lnw*4+qs -> write
// banks (lnw*16+qs*4+j/2)%32 = 2-way (free); frag reads are chunk-bijections
// (free). Park TRANSPOSED (Gram symmetric!) with packed b64 writes, then
// coalesced bf16 writeout.
// ---------------------------------------------------------------------------
__global__ __launch_bounds__(256, 2) void gram_partial_kernel(
    const float* __restrict__ feats, unsigned short* __restrict__ partial,
    int L, int KS) {
  const int g = blockIdx.x / KS;
  const int sl = blockIdx.x - g * KS;
  const int chunk = L / KS;
  const float* __restrict__ X = feats + ((size_t)g * L + (size_t)sl * chunk) * D;

  __shared__ __align__(16) unsigned short smem[16384];  // 32 KB (stage uses 16)
  const int tid = threadIdx.x;
  const int wv = tid >> 6, lane = tid & 63, quad = lane >> 4, ln = lane & 15;

  f32x4 acc[2][8];
#pragma unroll
  for (int rt = 0; rt < 2; ++rt)
#pragma unroll
    for (int ct = 0; ct < 8; ++ct) acc[rt][ct] = (f32x4)(0.f);

  // 1024 pair-tasks (32 k-pairs x 32 d4) per 64-row chunk, 4 per thread
  int k2v[4], d4v[4];
#pragma unroll
  for (int v = 0; v < 4; ++v) {
    int tt = tid + v * 256;
    k2v[v] = tt & 31;
    d4v[v] = tt >> 5;
  }
  float4 pf[8];
#pragma unroll
  for (int v = 0; v < 4; ++v) {
    pf[2 * v] = *(const float4*)(X + (size_t)(2 * k2v[v]) * D + 4 * d4v[v]);
    pf[2 * v + 1] = *(const float4*)(X + (size_t)(2 * k2v[v] + 1) * D + 4 * d4v[v]);
  }

  for (int it = 0; it < chunk; it += 64) {
    __syncthreads();
#pragma unroll
    for (int v = 0; v < 4; ++v) {
      const float* p0 = (const float*)&pf[2 * v];
      const float* p1 = (const float*)&pf[2 * v + 1];
      int k = 2 * k2v[v];
      int ks = k >> 5, kk = k & 31, qs = kk >> 3, j = kk & 7;
#pragma unroll
      for (int i = 0; i < 4; ++i) {
        int d = 4 * d4v[v] + i, t = d >> 4, lnw = d & 15;
        *(unsigned*)&smem[((ks * 8 + t) * 64 + lnw * 4 + qs) * 8 + j] =
            (unsigned)f2bf(p0[i]) | ((unsigned)f2bf(p1[i]) << 16);
      }
    }
    __syncthreads();
    if (it + 64 < chunk) {
      const float* Xn = X + (size_t)(it + 64) * D;
#pragma unroll
      for (int v = 0; v < 4; ++v) {
        pf[2 * v] = *(const float4*)(Xn + (size_t)(2 * k2v[v]) * D + 4 * d4v[v]);
        pf[2 * v + 1] =
            *(const float4*)(Xn + (size_t)(2 * k2v[v] + 1) * D + 4 * d4v[v]);
      }
    }
#pragma unroll
    for (int ks = 0; ks < 2; ++ks) {
      const int pos = (ln * 4 + quad) * 8;
      bf16x8 af[2], bfr[8];
      af[0] = *(const bf16x8*)&smem[(ks * 8 + 2 * wv) * 512 + pos];
      af[1] = *(const bf16x8*)&smem[(ks * 8 + 2 * wv + 1) * 512 + pos];
#pragma unroll
      for (int ct = 0; ct < 8; ++ct)
        bfr[ct] = *(const bf16x8*)&smem[(ks * 8 + ct) * 512 + pos];
#pragma unroll
      for (int rt = 0; rt < 2; ++rt)
#pragma unroll
        for (int ct = 0; ct < 8; ++ct)
          acc[rt][ct] = __builtin_amdgcn_mfma_f32_16x16x32_bf16(
              af[rt], bfr[ct], acc[rt][ct], 0, 0, 0);
    }
  }

  // park TRANSPOSED (valid: Gram symmetric) -> packed 8B writes, row-major out
  __syncthreads();
#pragma unroll
  for (int rt = 0; rt < 2; ++rt)
#pragma unroll
    for (int ct = 0; ct < 8; ++ct) {
      uint2 pk;
      pk.x = (unsigned)f2bf(acc[rt][ct][0]) |
             ((unsigned)f2bf(acc[rt][ct][1]) << 16);
      pk.y = (unsigned)f2bf(acc[rt][ct][2]) |
             ((unsigned)f2bf(acc[rt][ct][3]) << 16);
      *(uint2*)&smem[(16 * ct + ln) * 128 + 32 * wv + 16 * rt + quad * 4] = pk;
    }
  __syncthreads();
  unsigned short* P = partial + ((size_t)sl * GRAPHS + g) * (D * D);
#pragma unroll
  for (int v = 0; v < 8; ++v) {
    int idx = tid + v * 256;
    *(uint4*)&P[(size_t)idx * 8] = *(uint4*)&smem[idx * 8];
  }
}

// ---------------------------------------------------------------------------
// Fused main. grid = GRAPHS*(L/64) = 2048 blocks x 512 thr (8 waves).
// Wave (rowg=wv>>1, colg=wv&1) = 16 rows x 64 cols. A-frags loaded DIRECTLY
// global->register (no LDS for A; same frags used in both phases). G staged
// dest-major (conflict-free writes) summing KS bf16 partials in-register
// (absorbs reduce kernel); W2 computed in-kernel from w (absorbs w2 kernel).
// LDS = sVf 16K + sBf 32K = 48 KB.
// ---------------------------------------------------------------------------
__global__ __launch_bounds__(512, 4) void fused_kernel5(
    const float* __restrict__ feats, const unsigned short* __restrict__ partial,
    const float* __restrict__ w, float* __restrict__ out, int L, int KS) {
  const int tiles = L >> 6;
  const int gi = blockIdx.x / tiles;
  const int row0 = (blockIdx.x - gi * tiles) << 6;
  const int gx = gi ^ 1;
  const float* __restrict__ A = feats + ((size_t)gi * L + row0) * D;
  float* __restrict__ O = out + ((size_t)gi * L + row0) * D;

  __shared__ __align__(16) unsigned short sVf[8192];   // ((kc*4+rowg)*64+lane)*8
  __shared__ __align__(16) unsigned short sBf[16384];  // ((kc*8+tb)*64+lane)*8

  const int tid = threadIdx.x;
  const int wv = tid >> 6, lane = tid & 63, quad = lane >> 4, ln = lane & 15;
  const int rowg = wv >> 1, colg = wv & 1;

  // ---- A-frags: direct global -> registers (8 float4 per lane) ----
  U4H8 afr[4];
  {
    const float* Arow = A + (size_t)(rowg * 16 + ln) * D + quad * 8;
#pragma unroll
    for (int kc = 0; kc < 4; ++kc) {
      float4 t0 = *(const float4*)(Arow + kc * 32);
      float4 t1 = *(const float4*)(Arow + kc * 32 + 4);
      afr[kc].u.x = (unsigned)f2bf(t0.x) | ((unsigned)f2bf(t0.y) << 16);
      afr[kc].u.y = (unsigned)f2bf(t0.z) | ((unsigned)f2bf(t0.w) << 16);
      afr[kc].u.z = (unsigned)f2bf(t1.x) | ((unsigned)f2bf(t1.y) << 16);
      afr[kc].u.w = (unsigned)f2bf(t1.z) | ((unsigned)f2bf(t1.w) << 16);
    }
  }

  // ---- stage G = sum of KS bf16 partials, dest-major (conflict-free) ----
#pragma unroll
  for (int v = 0; v < 4; ++v) {
    int c = tid + v * 512;
    int slice = c >> 6, l64 = c & 63;
    int kc = slice >> 3, tb = slice & 7, qd = l64 >> 4, lnw = l64 & 15;
    int e = (tb * 16 + lnw) * D + kc * 32 + qd * 8;
    float s[8];
#pragma unroll
    for (int i = 0; i < 8; ++i) s[i] = 0.f;
    for (int slc = 0; slc < KS; ++slc) {
      uint4 t = *(const uint4*)&partial[((size_t)slc * GRAPHS + gx) * (D * D) + e];
      const unsigned* tp = &t.x;
#pragma unroll
      for (int q = 0; q < 4; ++q) {
        s[2 * q] += asf(tp[q] << 16);
        s[2 * q + 1] += asf(tp[q] & 0xFFFF0000u);
      }
    }
    uint4 o;
    o.x = (unsigned)f2bf(s[0]) | ((unsigned)f2bf(s[1]) << 16);
    o.y = (unsigned)f2bf(s[2]) | ((unsigned)f2bf(s[3]) << 16);
    o.z = (unsigned)f2bf(s[4]) | ((unsigned)f2bf(s[5]) << 16);
    o.w = (unsigned)f2bf(s[6]) | ((unsigned)f2bf(s[7]) << 16);
    *(uint4*)&sBf[c * 8] = o;
  }
  __syncthreads();

  // ---- phase 1: V2 = A * Gram (wave: 16 rows x 64 cols) ----
  f32x4 acc1[4];
#pragma unroll
  for (int c = 0; c < 4; ++c) acc1[c] = (f32x4)(0.f);
#pragma unroll
  for (int kc = 0; kc < 4; ++kc) {
#pragma unroll
    for (int c = 0; c < 4; ++c) {
      bf16x8 bfr =
          *(const bf16x8*)&sBf[((kc * 8 + colg * 4 + c) * 64 + lane) * 8];
      acc1[c] =
          __builtin_amdgcn_mfma_f32_16x16x32_bf16(afr[kc].h, bfr, acc1[c], 0, 0, 0);
    }
  }
  // park V2 (C-layout -> A-frag order)
#pragma unroll
  for (int c = 0; c < 4; ++c)
#pragma unroll
    for (int r = 0; r < 4; ++r) {
      int col = (colg * 4 + c) * 16 + ln;
      int kc_t = col >> 5, q_t = (col >> 3) & 3, j_t = col & 7;
      sVf[((kc_t * 4 + rowg) * 64 + q_t * 16 + quad * 4 + r) * 8 + j_t] =
          f2bf(acc1[c][r]);
    }
  __syncthreads();

  // ---- stage W2 = bf16(w^2), dest-major from fp32 w ----
#pragma unroll
  for (int v = 0; v < 4; ++v) {
    int c = tid + v * 512;
    int slice = c >> 6, l64 = c & 63;
    int kc = slice >> 3, tb = slice & 7, qd = l64 >> 4, lnw = l64 & 15;
    const float* src = w + (size_t)(tb * 16 + lnw) * D + kc * 32 + qd * 8;
    float4 a = *(const float4*)src;
    float4 b = *(const float4*)(src + 4);
    uint4 o;
    o.x = (unsigned)f2bf(a.x * a.x) | ((unsigned)f2bf(a.y * a.y) << 16);
    o.y = (unsigned)f2bf(a.z * a.z) | ((unsigned)f2bf(a.w * a.w) << 16);
    o.z = (unsigned)f2bf(b.x * b.x) | ((unsigned)f2bf(b.y * b.y) << 16);
    o.w = (unsigned)f2bf(b.z * b.z) | ((unsigned)f2bf(b.w * b.w) << 16);
    *(uint4*)&sBf[c * 8] = o;
  }
  __syncthreads();

  // ---- phase 2: three GEMMs vs W2 ----
  f32x4 an[4], s1[4], s2[4];
#pragma unroll
  for (int c = 0; c < 4; ++c) {
    an[c] = (f32x4)(0.f);
    s1[c] = (f32x4)(0.f);
    s2[c] = (f32x4)(0.f);
  }
#pragma unroll
  for (int dc = 0; dc < 4; ++dc) {
    uint4 uv = *(const uint4*)&sVf[((dc * 4 + rowg) * 64 + lane) * 8];
    U4H8 fx2, faa, fvv;
    const unsigned* uap = &afr[dc].u.x;
    const unsigned* uvp = &uv.x;
#pragma unroll
    for (int q = 0; q < 4; ++q) {
      float a0 = asf(uap[q] << 16), a1 = asf(uap[q] & 0xFFFF0000u);
      float v0 = asf(uvp[q] << 16), v1 = asf(uvp[q] & 0xFFFF0000u);
      (&fx2.u.x)[q] = __builtin_amdgcn_perm(asu(a1 * v1), asu(a0 * v0), 0x07060302u);
      (&faa.u.x)[q] = __builtin_amdgcn_perm(asu(a1 * a1), asu(a0 * a0), 0x07060302u);
      (&fvv.u.x)[q] = __builtin_amdgcn_perm(asu(v1 * v1), asu(v0 * v0), 0x07060302u);
    }
#pragma unroll
    for (int c = 0; c < 4; ++c) {
      bf16x8 wf = *(const bf16x8*)&sBf[((dc * 8 + colg * 4 + c) * 64 + lane) * 8];
      an[c] = __builtin_amdgcn_mfma_f32_16x16x32_bf16(fx2.h, wf, an[c], 0, 0, 0);
      s1[c] = __builtin_amdgcn_mfma_f32_16x16x32_bf16(faa.h, wf, s1[c], 0, 0, 0);
      s2[c] = __builtin_amdgcn_mfma_f32_16x16x32_bf16(fvv.h, wf, s2[c], 0, 0, 0);
    }
  }

  // ---- epilogue ----
#pragma unroll
  for (int c = 0; c < 4; ++c)
#pragma unroll
    for (int r = 0; r < 4; ++r) {
      float t = fmaxf(s1[c][r] * s2[c][r], 1e-16f);
      O[(size_t)(rowg * 16 + quad * 4 + r) * D + (colg * 4 + c) * 16 + ln] =
          an[c][r] * __builtin_amdgcn_rsqf(t);
    }
}

extern "C" void kernel_launch(void* const* d_in, const int* in_sizes, int n_in,
                              void* d_out, int out_size, void* d_ws, size_t ws_size,
                              hipStream_t stream) {
  const float* feats = (const float*)d_in[0];
  const float* w = (const float*)d_in[1];
  float* out = (float*)d_out;
  const int L = (in_sizes[0] / D) / GRAPHS;  // 2048

  const size_t partSlice = (size_t)GRAPHS * D * D * sizeof(unsigned short);  // 2 MiB
  int KS = 8;
  while (KS > 1 && (size_t)KS * partSlice > ws_size) KS >>= 1;

  unsigned short* partialBuf = (unsigned short*)d_ws;

  hipLaunchKernelGGL(gram_partial_kernel, dim3(GRAPHS * KS), dim3(256), 0,
                     stream, feats, partialBuf, L, KS);
  hipLaunchKernelGGL(fused_kernel5, dim3(GRAPHS * (L >> 6)), dim3(512), 0,
                     stream, feats, partialBuf, w, out, L, KS);
}